// Round 5
// baseline (2821.586 us; speedup 1.0000x reference)
//
#include <hip/hip_runtime.h>

#define NBATCH 16
#define NPTS   1024
#define NDIM   1024
#define EPSI   1e-3f
#define QSCALE 127.5f
#define SPIN_TIMEOUT_TICKS (1ull << 28)   // s_memrealtime ticks; >>1000x any real wait

typedef __attribute__((ext_vector_type(8))) short short8;
typedef __attribute__((ext_vector_type(4))) float f32x4;

__device__ __forceinline__ unsigned short f2bf(float f) {
  union { float f; unsigned u; } v; v.f = f;
  unsigned r = v.u + 0x7fffu + ((v.u >> 16) & 1u);
  return (unsigned short)(r >> 16);
}

// device-coherent scalar access (per-access sc bits; NO cache-wide fences)
__device__ __forceinline__ void st_agent(float* p, float v) {
  __hip_atomic_store(p, v, __ATOMIC_RELAXED, __HIP_MEMORY_SCOPE_AGENT);
}
__device__ __forceinline__ unsigned long long ld_agent64(const unsigned long long* p) {
  return __hip_atomic_load(p, __ATOMIC_RELAXED, __HIP_MEMORY_SCOPE_AGENT);
}

// ---------------- normalize: fp32 [B,N,D] -> unit rows, bf16 ----------------
__global__ __launch_bounds__(256) void norm_kernel(const float* __restrict__ x,
                                                   const float* __restrict__ y,
                                                   unsigned short* __restrict__ xf,
                                                   unsigned short* __restrict__ yf) {
  int row = blockIdx.x;
  const float* src; unsigned short* dst;
  if (row < NBATCH * NPTS) { src = x; dst = xf; }
  else { row -= NBATCH * NPTS; src = y; dst = yf; }
  src += (size_t)row * NDIM; dst += (size_t)row * NDIM;
  const int t = threadIdx.x;
  float4 val = ((const float4*)src)[t];
  float ss = val.x*val.x + val.y*val.y + val.z*val.z + val.w*val.w;
  #pragma unroll
  for (int o = 32; o; o >>= 1) ss += __shfl_xor(ss, o, 64);
  __shared__ float wsum[4];
  if ((t & 63) == 0) wsum[t >> 6] = ss;
  __syncthreads();
  float tot = wsum[0] + wsum[1] + wsum[2] + wsum[3];
  float inv = 1.0f / fmaxf(sqrtf(tot), 1e-12f);
  ushort4 o4;
  o4.x = f2bf(val.x * inv); o4.y = f2bf(val.y * inv);
  o4.z = f2bf(val.z * inv); o4.w = f2bf(val.w * inv);
  ((ushort4*)dst)[t] = o4;
}

// ------- batched bf16 GEMM: writes BOTH Cq = q8(1 - A B^T) and its transpose -------
#define GLD_LDS16(g, l) __builtin_amdgcn_global_load_lds( \
    (const __attribute__((address_space(1))) unsigned int*)(g), \
    (__attribute__((address_space(3))) unsigned int*)(l), 16, 0, 0)

__device__ __forceinline__ unsigned char q8(float cv) {
  float t = cv * QSCALE + 0.5f;
  t = fminf(fmaxf(t, 0.f), 255.f);
  return (unsigned char)(int)t;
}

__global__ __launch_bounds__(256) void gemm_cost(const unsigned short* __restrict__ A,
                                                 const unsigned short* __restrict__ B,
                                                 unsigned char* __restrict__ Cq,
                                                 unsigned char* __restrict__ CTq,
                                                 unsigned* __restrict__ cmax_bits) {
  const int b = blockIdx.z;
  const int bm = blockIdx.y * 128, bn = blockIdx.x * 128;
  const int t = threadIdx.x, lane = t & 63, wv = t >> 6;
  const int wm = (wv & 1) * 64, wn = (wv >> 1) * 64;
  __shared__ unsigned short As[128 * 32];
  __shared__ unsigned short Bs[128 * 32];
  f32x4 acc[4][4];
  #pragma unroll
  for (int i = 0; i < 4; ++i)
    #pragma unroll
    for (int j = 0; j < 4; ++j) acc[i][j] = (f32x4){0.f, 0.f, 0.f, 0.f};

  const unsigned short* gA = A + (size_t)b*NPTS*NDIM + (size_t)(bm + (t >> 2))*NDIM + (t & 3)*8;
  const unsigned short* gB = B + (size_t)b*NPTS*NDIM + (size_t)(bn + (t >> 2))*NDIM + (t & 3)*8;
  const int ar = lane & 15, ak = (lane >> 4) * 8;

  for (int k0 = 0; k0 < NDIM; k0 += 32) {
    GLD_LDS16(gA + k0,             As + t*8);
    GLD_LDS16(gA + 64*NDIM + k0,   As + 2048 + t*8);
    GLD_LDS16(gB + k0,             Bs + t*8);
    GLD_LDS16(gB + 64*NDIM + k0,   Bs + 2048 + t*8);
    __syncthreads();
    short8 af[4], bq[4];
    #pragma unroll
    for (int i = 0; i < 4; ++i) af[i] = *(const short8*)(As + (wm + i*16 + ar)*32 + ak);
    #pragma unroll
    for (int j = 0; j < 4; ++j) bq[j] = *(const short8*)(Bs + (wn + j*16 + ar)*32 + ak);
    #pragma unroll
    for (int i = 0; i < 4; ++i)
      #pragma unroll
      for (int j = 0; j < 4; ++j)
        acc[i][j] = __builtin_amdgcn_mfma_f32_16x16x32_bf16(af[i], bq[j], acc[i][j], 0, 0, 0);
    __syncthreads();
  }

  float mx = 0.f;
  const int cr = (lane >> 4) * 4, cc = lane & 15;
  unsigned char* Cb = Cq  + (size_t)b * NPTS * NPTS;
  unsigned char* Tb = CTq + (size_t)b * NPTS * NPTS;
  #pragma unroll
  for (int i = 0; i < 4; ++i) {
    #pragma unroll
    for (int j = 0; j < 4; ++j) {
      const int row0 = bm + wm + i*16 + cr;
      const int col  = bn + wn + j*16 + cc;
      #pragma unroll
      for (int r = 0; r < 4; ++r) {
        float cv = 1.0f - acc[i][j][r];
        mx = fmaxf(mx, cv);
        unsigned char qv = q8(cv);
        Cb[(size_t)(row0 + r) * NPTS + col] = qv;
        Tb[(size_t)col * NPTS + row0 + r]   = qv;
      }
    }
  }
  #pragma unroll
  for (int o = 32; o; o >>= 1) mx = fmaxf(mx, __shfl_xor(mx, o, 64));
  if (lane == 0) atomicMax(cmax_bits, __float_as_uint(mx));
}

// ---------------- persistent Sinkhorn: counter barrier + matrix-in-VGPR + LDS exchange ----------------
// 256 WGs x 512 thr. WG = (b, s) owns 64 COMPLETE outputs [s*64, s*64+64) of u and v.
// Matrix in VGPRs once (wave w, pass p -> row ob+w*8+p; lane l -> bytes [16l,16l+16)).
// Exchange: each thread coherent-loads ONE 8B pair of the published vector (4 KB/WG/phase,
// 8x less than round-4's per-wave full reads) into LDS at the bit-permuted slot
// (value m -> float idx ((m>>2)&3)*256 + (m>>4)*4 + (m&3)); every lane then reads its
// 16 g's as 4 contiguous conflict-free ds_read_b128 (layout proven in round 2).
// Early exit: once no WG's stored u/v changed bitwise over a full iteration, the
// remaining iterations are exact identities -> all WGs of the batch read the same
// cumulative change counter at the same phase and break identically.

__device__ __forceinline__ float dot16(uint4 q, f32x4 g0, f32x4 g1, f32x4 g2, f32x4 g3) {
  float a = 0.f;
  a += (float)( q.x        & 0xffu) * g0.x;   // v_cvt_f32_ubyte0
  a += (float)((q.x >>  8) & 0xffu) * g0.y;
  a += (float)((q.x >> 16) & 0xffu) * g0.z;
  a += (float)( q.x >> 24         ) * g0.w;
  a += (float)( q.y        & 0xffu) * g1.x;
  a += (float)((q.y >>  8) & 0xffu) * g1.y;
  a += (float)((q.y >> 16) & 0xffu) * g1.z;
  a += (float)( q.y >> 24         ) * g1.w;
  a += (float)( q.z        & 0xffu) * g2.x;
  a += (float)((q.z >>  8) & 0xffu) * g2.y;
  a += (float)((q.z >> 16) & 0xffu) * g2.z;
  a += (float)( q.z >> 24         ) * g2.w;
  a += (float)( q.w        & 0xffu) * g3.x;
  a += (float)((q.w >>  8) & 0xffu) * g3.y;
  a += (float)((q.w >> 16) & 0xffu) * g3.z;
  a += (float)( q.w >> 24         ) * g3.w;
  return a;
}

// stage this thread's 8B pair of the published vector into permuted LDS slot
__device__ __forceinline__ void stage_pair(const float* __restrict__ src, float* gst,
                                           int tid, int i0) {
  union { unsigned long long u; float f[2]; } c;
  c.u = ld_agent64((const unsigned long long*)src + tid);
  gst[i0]     = c.f[0];
  gst[i0 + 1] = c.f[1];
}

#define LOAD_G(buf)                                          \
  const f32x4 g0 = *(const f32x4*)&buf[      lane * 4];      \
  const f32x4 g1 = *(const f32x4*)&buf[256 + lane * 4];      \
  const f32x4 g2 = *(const f32x4*)&buf[512 + lane * 4];      \
  const f32x4 g3 = *(const f32x4*)&buf[768 + lane * 4];

__global__ __launch_bounds__(512) void sinkhorn_kernel(
    const unsigned char* __restrict__ Cq, const unsigned char* __restrict__ CTq,
    float* __restrict__ ubuf, float* __restrict__ vbuf,
    unsigned* __restrict__ bar, float* __restrict__ dist,
    const unsigned* __restrict__ cmax_bits)
{
  const int wg = blockIdx.x;
  const int b = wg & (NBATCH - 1);
  const int s = wg >> 4;
  const int ob = s * 64;
  const int tid = threadIdx.x, lane = tid & 63, w = tid >> 6;

  __shared__ __align__(16) float gst[1024];
  __shared__ float dred[8];
  __shared__ int s_tmo;       // sticky spin-timeout escape (container safety)
  __shared__ int s_chg;       // "this WG changed something this iteration"
  __shared__ unsigned s_chgval;
  if (tid == 0) { s_tmo = 0; s_chg = 0; }

  const float cmax  = __uint_as_float(*cmax_bits);
  const float invc2 = 1.0f / (QSCALE * cmax);   // dequant + /cmax folded

  // one-time matrix load into VGPRs: wave w, pass p -> row ob + w*8 + p
  uint4 mc[8], mt[8];
  {
    const unsigned char* cb = Cq  + (size_t)b * NPTS * NPTS;
    const unsigned char* tb = CTq + (size_t)b * NPTS * NPTS;
    #pragma unroll
    for (int p = 0; p < 8; ++p) {
      const size_t off = (size_t)(ob + w * 8 + p) * NPTS + lane * 16;
      mc[p] = *(const uint4*)(cb + off);
      mt[p] = *(const uint4*)(tb + off);
    }
  }

  float* ub = ubuf + b * NPTS;
  float* vb = vbuf + b * NPTS;
  unsigned* barb = bar + b * 64;       // 256-byte block per batch
  unsigned* chgp = barb + 16;          // change counter, separate 64B line

  // v#0 = 1/N (producers store final values)
  if (tid < 64) st_agent(&vb[ob + tid], 1.0f / (float)NPTS);
  {  // arrive
    __syncthreads();
    if (tid == 0)
      __hip_atomic_fetch_add(barb, 1u, __ATOMIC_RELEASE, __HIP_MEMORY_SCOPE_AGENT);
  }
  unsigned bt = 16;

  // permuted LDS slot for this thread's staged pair (values m=2*tid, 2*tid+1)
  const int i0 = ((tid >> 1) & 3) * 256 + (tid >> 3) * 4 + (tid & 1) * 2;

  float uk[8];                                   // u for our 8 rows (distance epilogue)
  float prev_us = __uint_as_float(0x7fc00000u);  // my stored u last iter (lane<8)
  float prev_vs = 1.0f / (float)NPTS;            // my stored v last iter (lane<8)
  unsigned prev_chg = 0xFFFFFFFFu;
  int early = 0;

  #pragma unroll 1
  for (int it = 0; it < 100; ++it) {
    // ---- U-wait: v#it published; also read cumulative change counter
    if (tid == 0) {
      if (!s_tmo) {
        int polls = 0;
        unsigned long long t0 = 0;
        while (__hip_atomic_load(barb, __ATOMIC_RELAXED, __HIP_MEMORY_SCOPE_AGENT) < bt) {
          if ((++polls & 63) == 0) {
            if (t0 == 0) t0 = __builtin_amdgcn_s_memrealtime();
            else if (__builtin_amdgcn_s_memrealtime() - t0 > SPIN_TIMEOUT_TICKS) { s_tmo = 1; break; }
            __builtin_amdgcn_s_sleep(1);
          }
        }
        asm volatile("" ::: "memory");
      }
      s_chgval = __hip_atomic_load(chgp, __ATOMIC_RELAXED, __HIP_MEMORY_SCOPE_AGENT);
      s_chg = 0;   // reset change flag for this iteration
    }
    __syncthreads();
    stage_pair(vb, gst, tid, i0);
    const unsigned chgnow = s_chgval;
    __syncthreads();

    // exact early exit: nothing changed bitwise last iteration -> frozen forever.
    // uk = u#(it-1) = final u; gst holds v#it = final v. All WGs break together.
    if (chgnow == prev_chg) { early = 1; break; }
    prev_chg = chgnow;

    // ---- U: u#it = 1/((Cq . v#it) * invc2 + eps)
    {
      LOAD_G(gst);
      float myv = 0.f;
      #pragma unroll
      for (int p = 0; p < 8; ++p) {
        float acc = dot16(mc[p], g0, g1, g2, g3);
        #pragma unroll
        for (int o = 32; o; o >>= 1) acc += __shfl_xor(acc, o, 64);
        const float val = 1.0f / (acc * invc2 + EPSI);
        uk[p] = val;
        myv = (lane == p) ? val : myv;
      }
      if (lane < 8) {
        st_agent(&ub[ob + w * 8 + lane], myv);
        if (__float_as_uint(myv) != __float_as_uint(prev_us)) s_chg = 1;
        prev_us = myv;
      }
    }
    __syncthreads();                       // arrive (stores drained per-wave)
    if (tid == 0)
      __hip_atomic_fetch_add(barb, 1u, __ATOMIC_RELEASE, __HIP_MEMORY_SCOPE_AGENT);
    bt += 16;

    // ---- V-wait: u#it published
    if (tid == 0) {
      if (!s_tmo) {
        int polls = 0;
        unsigned long long t0 = 0;
        while (__hip_atomic_load(barb, __ATOMIC_RELAXED, __HIP_MEMORY_SCOPE_AGENT) < bt) {
          if ((++polls & 63) == 0) {
            if (t0 == 0) t0 = __builtin_amdgcn_s_memrealtime();
            else if (__builtin_amdgcn_s_memrealtime() - t0 > SPIN_TIMEOUT_TICKS) { s_tmo = 1; break; }
            __builtin_amdgcn_s_sleep(1);
          }
        }
        asm volatile("" ::: "memory");
      }
    }
    __syncthreads();
    stage_pair(ub, gst, tid, i0);
    __syncthreads();

    // ---- V: v#(it+1) = 1/((CTq . u#it) * invc2 + eps)
    {
      LOAD_G(gst);
      float myv = 0.f;
      #pragma unroll
      for (int p = 0; p < 8; ++p) {
        float acc = dot16(mt[p], g0, g1, g2, g3);
        #pragma unroll
        for (int o = 32; o; o >>= 1) acc += __shfl_xor(acc, o, 64);
        const float val = 1.0f / (acc * invc2 + EPSI);
        myv = (lane == p) ? val : myv;
      }
      if (lane < 8) {
        st_agent(&vb[ob + w * 8 + lane], myv);
        if (__float_as_uint(myv) != __float_as_uint(prev_vs)) s_chg = 1;
        prev_vs = myv;
      }
    }
    __syncthreads();                       // arrive; release change-vote then counter
    if (tid == 0) {
      if (s_chg)
        __hip_atomic_fetch_add(chgp, 1u, __ATOMIC_RELAXED, __HIP_MEMORY_SCOPE_AGENT);
      __hip_atomic_fetch_add(barb, 1u, __ATOMIC_RELEASE, __HIP_MEMORY_SCOPE_AGENT);
    }
    bt += 16;
  }

  // ---- distance: d_b = sum_n u_n * (C_norm v)_n
  if (!early) {
    if (tid == 0) {
      if (!s_tmo) {
        int polls = 0;
        unsigned long long t0 = 0;
        while (__hip_atomic_load(barb, __ATOMIC_RELAXED, __HIP_MEMORY_SCOPE_AGENT) < bt) {
          if ((++polls & 63) == 0) {
            if (t0 == 0) t0 = __builtin_amdgcn_s_memrealtime();
            else if (__builtin_amdgcn_s_memrealtime() - t0 > SPIN_TIMEOUT_TICKS) { s_tmo = 1; break; }
            __builtin_amdgcn_s_sleep(1);
          }
        }
        asm volatile("" ::: "memory");
      }
    }
    __syncthreads();
    stage_pair(vb, gst, tid, i0);
    __syncthreads();
  }
  {
    LOAD_G(gst);
    float term = 0.f;
    #pragma unroll
    for (int p = 0; p < 8; ++p) {
      float acc = dot16(mc[p], g0, g1, g2, g3);
      #pragma unroll
      for (int o = 32; o; o >>= 1) acc += __shfl_xor(acc, o, 64);
      term += uk[p] * acc;     // butterfly leaves the sum in every lane
    }
    if (lane == 0) dred[w] = term;
    __syncthreads();
    if (tid == 0) {
      float d = 0.f;
      #pragma unroll
      for (int ww = 0; ww < 8; ++ww) d += dred[ww];
      atomicAdd(dist + b, d * invc2);
    }
  }
}

__global__ void finalize_kernel(const float* __restrict__ dist, float* __restrict__ out) {
  if (threadIdx.x == 0) {
    float s = 0.f;
    for (int i = 0; i < NBATCH; ++i) s += dist[i];
    out[0] = s * (1.0f / NBATCH);
  }
}

// ---------------- launch ----------------
extern "C" void kernel_launch(void* const* d_in, const int* in_sizes, int n_in,
                              void* d_out, int out_size, void* d_ws, size_t ws_size,
                              hipStream_t stream) {
  (void)in_sizes; (void)n_in; (void)out_size; (void)ws_size;
  const float* x = (const float*)d_in[0];
  const float* y = (const float*)d_in[1];
  float* out = (float*)d_out;
  char* ws = (char*)d_ws;

  unsigned* cmax_bits = (unsigned*)ws;                 // @0
  unsigned* bar       = (unsigned*)(ws + 4096);        // 16 x 256B blocks (bar + chg)
  float*    dist      = (float*)(ws + 8192);           // 16 floats
  float*    vbuf      = (float*)(ws + 65536);          // 16 x 1024 f32 = 64 KB
  float*    ubuf      = (float*)(ws + 131072);         // 64 KB
  const size_t MB = 1u << 20;
  unsigned short* xf = (unsigned short*)(ws + 1*MB);   // 32 MB bf16
  unsigned short* yf = (unsigned short*)(ws + 33*MB);  // 32 MB bf16
  unsigned char*  C  = (unsigned char*)(ws + 65*MB);   // 16 MB u8
  unsigned char*  CT = (unsigned char*)(ws + 81*MB);   // 16 MB u8

  hipMemsetAsync(d_ws, 0, 65536, stream);  // cmax / barriers / change counters / dist

  hipLaunchKernelGGL(norm_kernel, dim3(2 * NBATCH * NPTS), dim3(256), 0, stream, x, y, xf, yf);
  hipLaunchKernelGGL(gemm_cost, dim3(8, 8, NBATCH), dim3(256), 0, stream, xf, yf, C, CT, cmax_bits);
  hipLaunchKernelGGL(sinkhorn_kernel, dim3(256), dim3(512), 0, stream, C, CT, ubuf, vbuf, bar, dist, cmax_bits);
  hipLaunchKernelGGL(finalize_kernel, dim3(1), dim3(64), 0, stream, dist, out);
}

// Round 6
// 1225.678 us; speedup vs baseline: 2.3021x; 2.3021x over previous
//
#include <hip/hip_runtime.h>

#define NBATCH 16
#define NPTS   1024
#define NDIM   1024
#define EPSI   1e-3f
#define QSCALE 127.5f
#define SPIN_TIMEOUT_TICKS (1ull << 28)   // s_memrealtime ticks; >>1000x any real wait

typedef __attribute__((ext_vector_type(8))) short short8;
typedef __attribute__((ext_vector_type(4))) float f32x4;
typedef __attribute__((ext_vector_type(4))) unsigned uint32x4;

__device__ __forceinline__ unsigned short f2bf(float f) {
  union { float f; unsigned u; } v; v.f = f;
  unsigned r = v.u + 0x7fffu + ((v.u >> 16) & 1u);
  return (unsigned short)(r >> 16);
}

// device-coherent scalar access (per-access sc bits; NO cache-wide fences)
__device__ __forceinline__ void st_agent(float* p, float v) {
  __hip_atomic_store(p, v, __ATOMIC_RELAXED, __HIP_MEMORY_SCOPE_AGENT);
}
__device__ __forceinline__ unsigned long long ld_agent64(const unsigned long long* p) {
  return __hip_atomic_load(p, __ATOMIC_RELAXED, __HIP_MEMORY_SCOPE_AGENT);
}

// ---------------- normalize: fp32 [B,N,D] -> unit rows, bf16 ----------------
__global__ __launch_bounds__(256) void norm_kernel(const float* __restrict__ x,
                                                   const float* __restrict__ y,
                                                   unsigned short* __restrict__ xf,
                                                   unsigned short* __restrict__ yf) {
  int row = blockIdx.x;
  const float* src; unsigned short* dst;
  if (row < NBATCH * NPTS) { src = x; dst = xf; }
  else { row -= NBATCH * NPTS; src = y; dst = yf; }
  src += (size_t)row * NDIM; dst += (size_t)row * NDIM;
  const int t = threadIdx.x;
  float4 val = ((const float4*)src)[t];
  float ss = val.x*val.x + val.y*val.y + val.z*val.z + val.w*val.w;
  #pragma unroll
  for (int o = 32; o; o >>= 1) ss += __shfl_xor(ss, o, 64);
  __shared__ float wsum[4];
  if ((t & 63) == 0) wsum[t >> 6] = ss;
  __syncthreads();
  float tot = wsum[0] + wsum[1] + wsum[2] + wsum[3];
  float inv = 1.0f / fmaxf(sqrtf(tot), 1e-12f);
  ushort4 o4;
  o4.x = f2bf(val.x * inv); o4.y = f2bf(val.y * inv);
  o4.z = f2bf(val.z * inv); o4.w = f2bf(val.w * inv);
  ((ushort4*)dst)[t] = o4;
}

// ------- batched bf16 GEMM: writes BOTH Cq = q8(1 - A B^T) and its transpose -------
#define GLD_LDS16(g, l) __builtin_amdgcn_global_load_lds( \
    (const __attribute__((address_space(1))) unsigned int*)(g), \
    (__attribute__((address_space(3))) unsigned int*)(l), 16, 0, 0)

__device__ __forceinline__ unsigned char q8(float cv) {
  float t = cv * QSCALE + 0.5f;
  t = fminf(fmaxf(t, 0.f), 255.f);
  return (unsigned char)(int)t;
}

__global__ __launch_bounds__(256) void gemm_cost(const unsigned short* __restrict__ A,
                                                 const unsigned short* __restrict__ B,
                                                 unsigned char* __restrict__ Cq,
                                                 unsigned char* __restrict__ CTq,
                                                 unsigned* __restrict__ cmax_bits) {
  const int b = blockIdx.z;
  const int bm = blockIdx.y * 128, bn = blockIdx.x * 128;
  const int t = threadIdx.x, lane = t & 63, wv = t >> 6;
  const int wm = (wv & 1) * 64, wn = (wv >> 1) * 64;
  __shared__ unsigned short As[128 * 32];
  __shared__ unsigned short Bs[128 * 32];
  f32x4 acc[4][4];
  #pragma unroll
  for (int i = 0; i < 4; ++i)
    #pragma unroll
    for (int j = 0; j < 4; ++j) acc[i][j] = (f32x4){0.f, 0.f, 0.f, 0.f};

  const unsigned short* gA = A + (size_t)b*NPTS*NDIM + (size_t)(bm + (t >> 2))*NDIM + (t & 3)*8;
  const unsigned short* gB = B + (size_t)b*NPTS*NDIM + (size_t)(bn + (t >> 2))*NDIM + (t & 3)*8;
  const int ar = lane & 15, ak = (lane >> 4) * 8;

  for (int k0 = 0; k0 < NDIM; k0 += 32) {
    GLD_LDS16(gA + k0,             As + t*8);
    GLD_LDS16(gA + 64*NDIM + k0,   As + 2048 + t*8);
    GLD_LDS16(gB + k0,             Bs + t*8);
    GLD_LDS16(gB + 64*NDIM + k0,   Bs + 2048 + t*8);
    __syncthreads();
    short8 af[4], bq[4];
    #pragma unroll
    for (int i = 0; i < 4; ++i) af[i] = *(const short8*)(As + (wm + i*16 + ar)*32 + ak);
    #pragma unroll
    for (int j = 0; j < 4; ++j) bq[j] = *(const short8*)(Bs + (wn + j*16 + ar)*32 + ak);
    #pragma unroll
    for (int i = 0; i < 4; ++i)
      #pragma unroll
      for (int j = 0; j < 4; ++j)
        acc[i][j] = __builtin_amdgcn_mfma_f32_16x16x32_bf16(af[i], bq[j], acc[i][j], 0, 0, 0);
    __syncthreads();
  }

  float mx = 0.f;
  const int cr = (lane >> 4) * 4, cc = lane & 15;
  unsigned char* Cb = Cq  + (size_t)b * NPTS * NPTS;
  unsigned char* Tb = CTq + (size_t)b * NPTS * NPTS;
  #pragma unroll
  for (int i = 0; i < 4; ++i) {
    #pragma unroll
    for (int j = 0; j < 4; ++j) {
      const int row0 = bm + wm + i*16 + cr;
      const int col  = bn + wn + j*16 + cc;
      #pragma unroll
      for (int r = 0; r < 4; ++r) {
        float cv = 1.0f - acc[i][j][r];
        mx = fmaxf(mx, cv);
        unsigned char qv = q8(cv);
        Cb[(size_t)(row0 + r) * NPTS + col] = qv;
        Tb[(size_t)col * NPTS + row0 + r]   = qv;
      }
    }
  }
  #pragma unroll
  for (int o = 32; o; o >>= 1) mx = fmaxf(mx, __shfl_xor(mx, o, 64));
  if (lane == 0) atomicMax(cmax_bits, __float_as_uint(mx));
}

// -------- persistent Sinkhorn: ONE barrier per iteration (fused U+V partials) --------
// 256 WGs x 512 thr. WG (b,s) owns rows R = [s*64, s*64+64) of C.
// Per iteration (v#it replicated in LDS gst):
//   u_n = f(C[n,:].v)  for n in R           -- in-wave 1024-dot + butterfly, no sync
//   partial_m = sum_{n in R} C[n,m] u_n     -- CT rows in VGPRs; u via 64-float LDS hop
//   publish 4KB plane; ONE global barrier; every WG sums 16 planes (fixed order ->
//   bitwise identical), applies f -> v#(it+1), restages into permuted gst.
// u never crosses WGs. Distance = sum_m f(raw_m)*raw_m*invc2 (== u^T C~ v), computed
// in iteration 99's consumer step; WG s==0 writes it. Planes double-buffered by
// iteration parity (barrier causality makes WAR safe: write(it) requires all
// arrived(it-1), which postdates every read(it-2) of the same buffer).
// Poll = R0-proven s_sleep(1) EVERY poll (tight polling was R5's 13.4us/phase
// regression: 569MB of L2-miss poll traffic starving the producers' release-adds).

__device__ __forceinline__ float dot16(uint32x4 q, f32x4 g0, f32x4 g1, f32x4 g2, f32x4 g3) {
  float a = 0.f;
  a += (float)( q.x        & 0xffu) * g0.x;   // v_cvt_f32_ubyte0
  a += (float)((q.x >>  8) & 0xffu) * g0.y;
  a += (float)((q.x >> 16) & 0xffu) * g0.z;
  a += (float)( q.x >> 24         ) * g0.w;
  a += (float)( q.y        & 0xffu) * g1.x;
  a += (float)((q.y >>  8) & 0xffu) * g1.y;
  a += (float)((q.y >> 16) & 0xffu) * g1.z;
  a += (float)( q.y >> 24         ) * g1.w;
  a += (float)( q.z        & 0xffu) * g2.x;
  a += (float)((q.z >>  8) & 0xffu) * g2.y;
  a += (float)((q.z >> 16) & 0xffu) * g2.z;
  a += (float)( q.z >> 24         ) * g2.w;
  a += (float)( q.w        & 0xffu) * g3.x;
  a += (float)((q.w >>  8) & 0xffu) * g3.y;
  a += (float)((q.w >> 16) & 0xffu) * g3.z;
  a += (float)( q.w >> 24         ) * g3.w;
  return a;
}

#define LOAD_G(buf)                                          \
  const f32x4 g0 = *(const f32x4*)&buf[      lane * 4];      \
  const f32x4 g1 = *(const f32x4*)&buf[256 + lane * 4];      \
  const f32x4 g2 = *(const f32x4*)&buf[512 + lane * 4];      \
  const f32x4 g3 = *(const f32x4*)&buf[768 + lane * 4];

__global__ __launch_bounds__(512) void sinkhorn_kernel(
    const unsigned char* __restrict__ Cq, const unsigned char* __restrict__ CTq,
    float* __restrict__ part, unsigned* __restrict__ bar, float* __restrict__ dist,
    const unsigned* __restrict__ cmax_bits)
{
  const int wg = blockIdx.x;
  const int b = wg & (NBATCH - 1);
  const int s = wg >> 4;
  const int ob = s * 64;
  const int tid = threadIdx.x, lane = tid & 63, w = tid >> 6;

  __shared__ __align__(16) float gst[1024];
  __shared__ __align__(16) float lds_u[64];
  __shared__ float dred[8];
  __shared__ int s_tmo;
  if (tid == 0) s_tmo = 0;

  const float cmax  = __uint_as_float(*cmax_bits);
  const float invc2 = 1.0f / (QSCALE * cmax);   // dequant + /cmax folded

  // one-time matrix load: mc = 8 C-rows (row ob+w*8+p, bytes [16l,16l+16));
  // md0/md1 = 2 CT-rows per lane (C-cols c0 = w*128+lane, c1 = c0+64), cols ob..ob+63
  uint32x4 mc[8];
  {
    const unsigned char* cb = Cq + (size_t)b * NPTS * NPTS;
    #pragma unroll
    for (int p = 0; p < 8; ++p)
      mc[p] = *(const uint32x4*)(cb + (size_t)(ob + w * 8 + p) * NPTS + lane * 16);
  }
  uint32x4 md0[4], md1[4];
  {
    const unsigned char* tb = CTq + (size_t)b * NPTS * NPTS;
    const int c0 = w * 128 + lane;
    #pragma unroll
    for (int j = 0; j < 4; ++j) {
      md0[j] = *(const uint32x4*)(tb + (size_t)c0 * NPTS + ob + j * 16);
      md1[j] = *(const uint32x4*)(tb + (size_t)(c0 + 64) * NPTS + ob + j * 16);
    }
  }

  unsigned* barb = bar + b * 64;      // 256-byte block per batch

  // v#0 = 1/N replicated (constant, permutation irrelevant)
  gst[tid]       = 1.0f / (float)NPTS;
  gst[tid + 512] = 1.0f / (float)NPTS;
  // permuted gst slot for this thread's 2 values (m = 2*tid, 2*tid+1) -- proven R2/R5
  const int i0 = ((tid >> 1) & 3) * 256 + (tid >> 3) * 4 + (tid & 1) * 2;
  __syncthreads();

  unsigned bt = 16;
  #pragma unroll 1
  for (int it = 0; it < 100; ++it) {
    // ---- u_n = f(C[n,:].v#it) for our 8 rows (per wave)
    LOAD_G(gst);
    float myu = 0.f;
    #pragma unroll
    for (int p = 0; p < 8; ++p) {
      float acc = dot16(mc[p], g0, g1, g2, g3);
      #pragma unroll
      for (int o = 32; o; o >>= 1) acc += __shfl_xor(acc, o, 64);
      const float val = 1.0f / (acc * invc2 + EPSI);
      myu = (lane == p) ? val : myu;
    }
    if (lane < 8) lds_u[w * 8 + lane] = myu;
    __syncthreads();

    // ---- partial_m = sum_{n in R} CT[m,n] u_n for this lane's 2 columns
    float p0 = 0.f, p1 = 0.f;
    #pragma unroll
    for (int q = 0; q < 16; ++q) {
      const float4 uq = *(const float4*)&lds_u[4 * q];   // broadcast read
      const unsigned d0 = md0[q >> 2][q & 3];
      const unsigned d1 = md1[q >> 2][q & 3];
      p0 += (float)( d0        & 0xffu) * uq.x;
      p0 += (float)((d0 >>  8) & 0xffu) * uq.y;
      p0 += (float)((d0 >> 16) & 0xffu) * uq.z;
      p0 += (float)( d0 >> 24         ) * uq.w;
      p1 += (float)( d1        & 0xffu) * uq.x;
      p1 += (float)((d1 >>  8) & 0xffu) * uq.y;
      p1 += (float)((d1 >> 16) & 0xffu) * uq.z;
      p1 += (float)( d1 >> 24         ) * uq.w;
    }
    float* pw = part + ((size_t)((it & 1) * NBATCH + b) * 16 + s) * 1024 + w * 128;
    st_agent(pw + lane,      p0);
    st_agent(pw + 64 + lane, p1);

    // ---- ONE global barrier (arrive after per-wave vmcnt(0) drain; R0-proven)
    __syncthreads();
    if (tid == 0) {
      __hip_atomic_fetch_add(barb, 1u, __ATOMIC_RELEASE, __HIP_MEMORY_SCOPE_AGENT);
      if (!s_tmo) {
        int polls = 0; unsigned long long t0 = 0;
        while (__hip_atomic_load(barb, __ATOMIC_RELAXED, __HIP_MEMORY_SCOPE_AGENT) < bt) {
          __builtin_amdgcn_s_sleep(1);
          if ((++polls & 63) == 0) {
            if (!t0) t0 = __builtin_amdgcn_s_memrealtime();
            else if (__builtin_amdgcn_s_memrealtime() - t0 > SPIN_TIMEOUT_TICKS) { s_tmo = 1; break; }
          }
        }
      }
      asm volatile("" ::: "memory");
    }
    __syncthreads();
    bt += 16;

    // ---- consume: sum 16 planes (fixed order), f(), restage v#(it+1)
    const float* prb = part + (size_t)((it & 1) * NBATCH + b) * 16 * 1024;
    float r0 = 0.f, r1 = 0.f;
    #pragma unroll
    for (int q = 0; q < 16; ++q) {
      union { unsigned long long u; float f[2]; } c;
      c.u = ld_agent64((const unsigned long long*)(prb + q * 1024) + tid);
      r0 += c.f[0]; r1 += c.f[1];
    }
    const float v0 = 1.0f / (r0 * invc2 + EPSI);
    const float v1 = 1.0f / (r1 * invc2 + EPSI);
    gst[i0]     = v0;
    gst[i0 + 1] = v1;

    if (it == 99 && s == 0) {   // distance: sum_m f(raw_m)*raw_m*invc2 == u^T C~ v
      float dterm = v0 * r0 + v1 * r1;
      #pragma unroll
      for (int o = 32; o; o >>= 1) dterm += __shfl_xor(dterm, o, 64);
      if (lane == 0) dred[w] = dterm;
    }
    __syncthreads();
  }

  if (s == 0 && tid == 0) {
    float d = 0.f;
    #pragma unroll
    for (int ww = 0; ww < 8; ++ww) d += dred[ww];
    st_agent(&dist[b], d * invc2);
  }
}

__global__ void finalize_kernel(const float* __restrict__ dist, float* __restrict__ out) {
  if (threadIdx.x == 0) {
    float s = 0.f;
    for (int i = 0; i < NBATCH; ++i) s += dist[i];
    out[0] = s * (1.0f / NBATCH);
  }
}

// ---------------- launch ----------------
extern "C" void kernel_launch(void* const* d_in, const int* in_sizes, int n_in,
                              void* d_out, int out_size, void* d_ws, size_t ws_size,
                              hipStream_t stream) {
  (void)in_sizes; (void)n_in; (void)out_size; (void)ws_size;
  const float* x = (const float*)d_in[0];
  const float* y = (const float*)d_in[1];
  float* out = (float*)d_out;
  char* ws = (char*)d_ws;

  unsigned* cmax_bits = (unsigned*)ws;                 // @0
  unsigned* bar       = (unsigned*)(ws + 4096);        // 16 x 256B counters
  float*    dist      = (float*)(ws + 8192);           // 16 floats
  const size_t MB = 1u << 20;
  float*    part      = (float*)(ws + 2*MB);           // [2][16][16][1024] f32 = 2 MB
                                                       // (inside xf region; xf dead by then)
  unsigned short* xf = (unsigned short*)(ws + 1*MB);   // 32 MB bf16 (norm/gemm only)
  unsigned short* yf = (unsigned short*)(ws + 33*MB);  // 32 MB bf16 (norm/gemm only)
  unsigned char*  C  = (unsigned char*)(ws + 65*MB);   // 16 MB u8
  unsigned char*  CT = (unsigned char*)(ws + 81*MB);   // 16 MB u8

  hipMemsetAsync(d_ws, 0, 65536, stream);  // cmax / barriers / dist

  hipLaunchKernelGGL(norm_kernel, dim3(2 * NBATCH * NPTS), dim3(256), 0, stream, x, y, xf, yf);
  hipLaunchKernelGGL(gemm_cost, dim3(8, 8, NBATCH), dim3(256), 0, stream, xf, yf, C, CT, cmax_bits);
  hipLaunchKernelGGL(sinkhorn_kernel, dim3(256), dim3(512), 0, stream, C, CT, part, bar, dist, cmax_bits);
  hipLaunchKernelGGL(finalize_kernel, dim3(1), dim3(64), 0, stream, dist, out);
}